// Round 12
// baseline (109.037 us; speedup 1.0000x reference)
//
#include <hip/hip_runtime.h>
#include <hip/hip_bf16.h>

// B=8, N=128, M=256, E=256, De=64, H=8, D=32
#define INV_SCALE 0.17677669529663687f
#define LN_EPS 1e-5f

typedef unsigned int uint;
typedef unsigned short ushort;
typedef __attribute__((ext_vector_type(8))) short bf16x8;   // MFMA A/B frag
typedef __attribute__((ext_vector_type(4))) float f32x4;    // MFMA C/D frag

union U8 { bf16x8 v; uint4 u4; ushort us[8]; };

__device__ __forceinline__ ushort bfround(float f) {
  uint u = __float_as_uint(f);
  u += 0x7fffu + ((u >> 16) & 1u);
  return (ushort)(u >> 16);
}
__device__ __forceinline__ uint pkbf(float a, float b) {
  uint ua = __float_as_uint(a); ua += 0x7fffu + ((ua >> 16) & 1u);
  uint ub = __float_as_uint(b); ub += 0x7fffu + ((ub >> 16) & 1u);
  return (ua >> 16) | (ub & 0xffff0000u);
}
__device__ __forceinline__ float bs(ushort u) { return __uint_as_float(((uint)u) << 16); }

// ---------------- Kernel 1: Q/K/V projections (round-5-proven) ----------------
__global__ __launch_bounds__(256) void proj3_kernel(
    const float* __restrict__ q, const float* __restrict__ k, const float* __restrict__ v,
    const float* __restrict__ wq, const float* __restrict__ wk, const float* __restrict__ wv,
    ushort* __restrict__ Qb, ushort* __restrict__ Kb, ushort* __restrict__ VtB) {
  constexpr int RPB = 8;
  __shared__ float in_s[RPB][256];
  int blk = blockIdx.x;
  int t = threadIdx.x;
  const float* in; const float* w; int r0;
  if (blk < 128)      { in = q; w = wq; r0 = blk * RPB; }
  else if (blk < 384) { in = k; w = wk; r0 = (blk - 128) * RPB; }
  else                { in = v; w = wv; r0 = (blk - 384) * RPB; }
  #pragma unroll
  for (int r = 0; r < RPB; ++r) in_s[r][t] = in[(size_t)(r0 + r) * 256 + t];
  __syncthreads();
  float acc[RPB];
  #pragma unroll
  for (int r = 0; r < RPB; ++r) acc[r] = 0.f;
  const float4* wrow = reinterpret_cast<const float4*>(w + (size_t)t * 256);
  for (int j4 = 0; j4 < 64; ++j4) {
    float4 wv4 = wrow[j4];
    #pragma unroll
    for (int r = 0; r < RPB; ++r) {
      float4 iv = *reinterpret_cast<const float4*>(&in_s[r][j4 * 4]);
      acc[r] += wv4.x * iv.x + wv4.y * iv.y + wv4.z * iv.z + wv4.w * iv.w;
    }
  }
  if (blk < 128) {
    #pragma unroll
    for (int r = 0; r < RPB; ++r) Qb[(size_t)(r0 + r) * 256 + t] = bfround(acc[r]);
  } else if (blk < 384) {
    #pragma unroll
    for (int r = 0; r < RPB; ++r) Kb[(size_t)(r0 + r) * 256 + t] = bfround(acc[r]);
  } else {
    int b = r0 >> 8, m0 = r0 & 255;
    uint4 pk;
    pk.x = pkbf(acc[0], acc[1]); pk.y = pkbf(acc[2], acc[3]);
    pk.z = pkbf(acc[4], acc[5]); pk.w = pkbf(acc[6], acc[7]);
    *(uint4*)(VtB + ((size_t)(b * 256 + t)) * 256 + m0) = pk;
  }
}

// ---------------- Kernel 1b: qep[bn][h*64+de] ----------------
__global__ __launch_bounds__(256) void qep_kernel(
    const ushort* __restrict__ Qb, const float* __restrict__ ep_w,
    ushort* __restrict__ qepb) {
  __shared__ float Qs[256];
  int bn = blockIdx.x, t = threadIdx.x;
  Qs[t] = bs(Qb[(size_t)bn * 256 + t]);
  __syncthreads();
  #pragma unroll
  for (int rep = 0; rep < 2; ++rep) {
    int idx = rep * 256 + t;
    int h = idx >> 6, de = idx & 63;
    float acc = 0.f;
    #pragma unroll
    for (int d = 0; d < 32; ++d)
      acc += Qs[h * 32 + d] * ep_w[(size_t)(h * 32 + d) * 64 + de];
    qepb[(size_t)bn * 512 + idx] = bfround(acc);
  }
}

// ---------------- Kernel 1c: qk[bn][h][m] = Q.K (blockdiag-masked MFMA) ----------------
// grid 2048 = (b:8, ng:32, mc:8). No LDS; K chunk L2-hot (shared by 32 blocks).
__global__ __launch_bounds__(256) void qk_kernel(
    const ushort* __restrict__ Qb, const ushort* __restrict__ Kb,
    float* __restrict__ qk) {
  const int bid = blockIdx.x;
  const int b = bid >> 8, ng = (bid >> 3) & 31, mc = bid & 7;
  const int t = threadIdx.x;
  const int w = t >> 6, l = t & 63, g = l >> 4, c = l & 15;
  const int bn = b * 128 + ng * 4 + w;
  const int m0 = mc * 32;
  U8 aQ; aQ.u4 = *(const uint4*)(Qb + (size_t)bn * 256 + (c & 7) * 32 + g * 8);
  U8 zf; zf.u4 = make_uint4(0u, 0u, 0u, 0u);
  #pragma unroll
  for (int mt = 0; mt < 2; ++mt) {
    const ushort* krow = Kb + ((size_t)(b * 256 + m0 + mt * 16 + c)) * 256 + g * 8;
    U8 kf[8];
    #pragma unroll
    for (int s = 0; s < 8; ++s) kf[s].u4 = *(const uint4*)(krow + s * 32);
    f32x4 acc; acc.x = acc.y = acc.z = acc.w = 0.f;
    #pragma unroll
    for (int s = 0; s < 8; ++s)
      acc = __builtin_amdgcn_mfma_f32_16x16x32_bf16((c == s) ? aQ.v : zf.v, kf[s].v, acc, 0, 0, 0);
    if (g < 2) {
      #pragma unroll
      for (int r = 0; r < 4; ++r)
        qk[(size_t)bn * 2048 + (size_t)(g * 4 + r) * 256 + m0 + mt * 16 + c] = acc[r];
    }
  }
}

// ---------------- Kernel 2: slim partial MFMA attention ----------------
// grid 2048 = (b:8, ng:32, mc:8). 256 thr = 4 waves; wave-private LDS, no barriers.
// QK precomputed (qk_kernel): score chain = 2 edge MFMAs + add. VtB frags
// preloaded (T14 hoist). Unnormalized exp; partials additive across mc.
__global__ __launch_bounds__(256, 3) void attn_part_kernel(
    const ushort* __restrict__ VtB, const ushort* __restrict__ qepb,
    const float* __restrict__ qk, const float* __restrict__ edge,
    ushort* __restrict__ ctxVp, ushort* __restrict__ attEp, float* __restrict__ S_p) {
  __shared__ ushort etr_s[4][64][38];   // [de][m] transposed edge, wave-private
  __shared__ ushort p_s[4][16][40];     // [h][m]

  const int bid = blockIdx.x;
  const int b = bid >> 8, ng = (bid >> 3) & 31, mc = bid & 7;
  const int t = threadIdx.x;
  const int w = t >> 6, l = t & 63, g = l >> 4, c = l & 15;
  const int bn = b * 128 + ng * 4 + w;
  const int m0 = mc * 32;
  const size_t pidx = (size_t)bn * 8 + mc;

  // ---- issue qk loads first (8 dwords, dup rows for g>=2) ----
  float qkv[2][4];
  #pragma unroll
  for (int mt = 0; mt < 2; ++mt)
    #pragma unroll
    for (int r = 0; r < 4; ++r)
      qkv[mt][r] = qk[(size_t)bn * 2048 + (size_t)((g * 4 + r) & 7) * 256 + m0 + mt * 16 + c];

  // ---- qep A-fragments ----
  U8 aE0; aE0.u4 = *(const uint4*)(qepb + (size_t)bn * 512 + (c & 7) * 64 + g * 8);
  U8 aE1; aE1.u4 = *(const uint4*)(qepb + (size_t)bn * 512 + (c & 7) * 64 + 32 + g * 8);

  // ---- stage transposed edge chunk (fp32 -> bf16), wave-private ----
  {
    const float* ebase = edge + ((size_t)bn * 256 + m0) * 64 + c * 4;
    #pragma unroll
    for (int i = 0; i < 2; ++i) {
      int mb = i * 16 + g * 4;
      const float* src = ebase + (size_t)mb * 64;
      float4 e0 = *(const float4*)(src);
      float4 e1 = *(const float4*)(src + 64);
      float4 e2 = *(const float4*)(src + 128);
      float4 e3 = *(const float4*)(src + 192);
      int de4 = c * 4;
      *(uint*)&etr_s[w][de4 + 0][mb]     = pkbf(e0.x, e1.x);
      *(uint*)&etr_s[w][de4 + 0][mb + 2] = pkbf(e2.x, e3.x);
      *(uint*)&etr_s[w][de4 + 1][mb]     = pkbf(e0.y, e1.y);
      *(uint*)&etr_s[w][de4 + 1][mb + 2] = pkbf(e2.y, e3.y);
      *(uint*)&etr_s[w][de4 + 2][mb]     = pkbf(e0.z, e1.z);
      *(uint*)&etr_s[w][de4 + 2][mb + 2] = pkbf(e2.z, e3.z);
      *(uint*)&etr_s[w][de4 + 3][mb]     = pkbf(e0.w, e1.w);
      *(uint*)&etr_s[w][de4 + 3][mb + 2] = pkbf(e2.w, e3.w);
    }
  }

  // ---- hoist all 16 VtB B-fragments (independent of p; in flight over scores) ----
  U8 bv[16];
  #pragma unroll
  for (int et = 0; et < 16; ++et)
    bv[et].u4 = *(const uint4*)(VtB + ((size_t)(b * 256 + et * 16 + c)) * 256 + m0 + g * 8);

  // ---- scores + exp: 2-deep edge MFMA + qk add ----
  float sS[4] = {0.f, 0.f, 0.f, 0.f};
  #pragma unroll
  for (int mt = 0; mt < 2; ++mt) {
    const float* erow = edge + ((size_t)bn * 256 + (m0 + mt * 16 + c)) * 64 + g * 8;
    float4 x0 = *(const float4*)(erow);
    float4 x1 = *(const float4*)(erow + 4);
    float4 x2 = *(const float4*)(erow + 32);
    float4 x3 = *(const float4*)(erow + 36);
    U8 be0, be1;
    be0.u4.x = pkbf(x0.x, x0.y); be0.u4.y = pkbf(x0.z, x0.w);
    be0.u4.z = pkbf(x1.x, x1.y); be0.u4.w = pkbf(x1.z, x1.w);
    be1.u4.x = pkbf(x2.x, x2.y); be1.u4.y = pkbf(x2.z, x2.w);
    be1.u4.z = pkbf(x3.x, x3.y); be1.u4.w = pkbf(x3.z, x3.w);
    f32x4 acc; acc.x = acc.y = acc.z = acc.w = 0.f;
    acc = __builtin_amdgcn_mfma_f32_16x16x32_bf16(aE0.v, be0.v, acc, 0, 0, 0);
    acc = __builtin_amdgcn_mfma_f32_16x16x32_bf16(aE1.v, be1.v, acc, 0, 0, 0);
    #pragma unroll
    for (int r = 0; r < 4; ++r) {
      float p = __expf((acc[r] + qkv[mt][r]) * INV_SCALE);
      p_s[w][g * 4 + r][mt * 16 + c] = bfround(p);
      sS[r] += p;
    }
  }
  #pragma unroll
  for (int r = 0; r < 4; ++r) {
    float sv = sS[r];
    sv += __shfl_xor(sv, 1); sv += __shfl_xor(sv, 2);
    sv += __shfl_xor(sv, 4); sv += __shfl_xor(sv, 8);
    sS[r] = sv;
  }
  if (c == 0 && g < 2) {
    #pragma unroll
    for (int r = 0; r < 4; ++r) S_p[pidx * 8 + g * 4 + r] = sS[r];
  }

  // ---- PV: ctxV partial (16 e-tiles, preloaded frags) ----
  U8 pa; pa.u4 = *(const uint4*)&p_s[w][c][g * 8];
  #pragma unroll
  for (int et = 0; et < 16; ++et) {
    f32x4 acc; acc.x = acc.y = acc.z = acc.w = 0.f;
    acc = __builtin_amdgcn_mfma_f32_16x16x32_bf16(pa.v, bv[et].v, acc, 0, 0, 0);
    int hs = et >> 1;
    if ((hs >> 2) == g) ctxVp[pidx * 256 + et * 16 + c] = bfround(acc[hs & 3]);
  }
  // ---- attnE partial (4 de-tiles, edge^T from wave-private LDS) ----
  #pragma unroll
  for (int dt = 0; dt < 4; ++dt) {
    U8 bt;
    bt.u4.x = *(const uint*)&etr_s[w][dt * 16 + c][g * 8 + 0];
    bt.u4.y = *(const uint*)&etr_s[w][dt * 16 + c][g * 8 + 2];
    bt.u4.z = *(const uint*)&etr_s[w][dt * 16 + c][g * 8 + 4];
    bt.u4.w = *(const uint*)&etr_s[w][dt * 16 + c][g * 8 + 6];
    f32x4 acc; acc.x = acc.y = acc.z = acc.w = 0.f;
    acc = __builtin_amdgcn_mfma_f32_16x16x32_bf16(pa.v, bt.v, acc, 0, 0, 0);
    if (g < 2) {
      #pragma unroll
      for (int r = 0; r < 4; ++r)
        attEp[pidx * 512 + (size_t)(g * 4 + r) * 64 + dt * 16 + c] = bfround(acc[r]);
    }
  }
}

// ---------------- Kernel 3: reduce partials + ep fold + out-proj + LN ----------------
__global__ __launch_bounds__(256) void reduce_outln_kernel(
    const ushort* __restrict__ ctxVp, const ushort* __restrict__ attEp,
    const float* __restrict__ S_p, const float* __restrict__ ep_w,
    const float* __restrict__ ep_b, const float* __restrict__ wo_w,
    const float* __restrict__ wo_b, const float* __restrict__ qin,
    const float* __restrict__ ln_g, const float* __restrict__ ln_b,
    float* __restrict__ out) {
  __shared__ float aE_s[2][512];
  __shared__ float ctx_s[2][256];
  __shared__ float o_s[2][256];
  __shared__ float rs_s[2][8];
  int bn0 = blockIdx.x * 2;
  int t = threadIdx.x;
  float cv[2];
  #pragma unroll
  for (int r = 0; r < 2; ++r) {
    float a0 = 0, a1 = 0, cc = 0;
    #pragma unroll
    for (int mcc = 0; mcc < 8; ++mcc) {
      size_t base = (size_t)(bn0 + r) * 8 + mcc;
      a0 += bs(attEp[base * 512 + t]);
      a1 += bs(attEp[base * 512 + 256 + t]);
      cc += bs(ctxVp[base * 256 + t]);
    }
    aE_s[r][t] = a0; aE_s[r][256 + t] = a1; cv[r] = cc;
  }
  if (t < 16) {
    int r = t >> 3, h = t & 7;
    float s = 0.f;
    #pragma unroll
    for (int mcc = 0; mcc < 8; ++mcc)
      s += S_p[((size_t)(bn0 + r) * 8 + mcc) * 8 + h];
    rs_s[r][h] = 1.f / s;
  }
  __syncthreads();
  {
    int h = t >> 5;
    const float* wrow = ep_w + (size_t)t * 64;
    float acc[2] = {0.f, 0.f};
    #pragma unroll
    for (int de4 = 0; de4 < 16; ++de4) {
      float4 w4 = *(const float4*)(wrow + de4 * 4);
      #pragma unroll
      for (int r = 0; r < 2; ++r) {
        float4 a4 = *(const float4*)&aE_s[r][h * 64 + de4 * 4];
        acc[r] += w4.x * a4.x + w4.y * a4.y + w4.z * a4.z + w4.w * a4.w;
      }
    }
    #pragma unroll
    for (int r = 0; r < 2; ++r)
      ctx_s[r][t] = (cv[r] + acc[r]) * rs_s[r][h] + ep_b[t];
  }
  __syncthreads();
  {
    const float4* wrow = (const float4*)(wo_w + (size_t)t * 256);
    float acc[2] = {0.f, 0.f};
    for (int j4 = 0; j4 < 64; ++j4) {
      float4 w4 = wrow[j4];
      #pragma unroll
      for (int r = 0; r < 2; ++r) {
        float4 iv = *(const float4*)&ctx_s[r][j4 * 4];
        acc[r] += w4.x * iv.x + w4.y * iv.y + w4.z * iv.z + w4.w * iv.w;
      }
    }
    float bias = wo_b[t];
    #pragma unroll
    for (int r = 0; r < 2; ++r)
      o_s[r][t] = acc[r] + bias + qin[(size_t)(bn0 + r) * 256 + t];
  }
  __syncthreads();
  {
    int wv = t >> 6, l = t & 63;
    if (wv < 2) {
      int r = wv;
      float sum = 0.f, sq = 0.f;
      #pragma unroll
      for (int kk = 0; kk < 4; ++kk) {
        float x = o_s[r][l + kk * 64];
        sum += x; sq += x * x;
      }
      #pragma unroll
      for (int ofs = 32; ofs; ofs >>= 1) {
        sum += __shfl_xor(sum, ofs);
        sq  += __shfl_xor(sq, ofs);
      }
      float mu = sum * (1.f / 256.f);
      float var = sq * (1.f / 256.f) - mu * mu;
      float rstd = rsqrtf(var + LN_EPS);
      #pragma unroll
      for (int kk = 0; kk < 4; ++kk) {
        int e = l + kk * 64;
        float x = o_s[r][e];
        out[(size_t)(bn0 + r) * 256 + e] = (x - mu) * rstd * ln_g[e] + ln_b[e];
      }
    }
  }
}

extern "C" void kernel_launch(void* const* d_in, const int* in_sizes, int n_in,
                              void* d_out, int out_size, void* d_ws, size_t ws_size,
                              hipStream_t stream) {
  const float* q    = (const float*)d_in[0];
  const float* k    = (const float*)d_in[1];
  const float* v    = (const float*)d_in[2];
  const float* edge = (const float*)d_in[3];
  const float* wq   = (const float*)d_in[4];
  const float* wk   = (const float*)d_in[5];
  const float* wv   = (const float*)d_in[6];
  const float* wo_w = (const float*)d_in[7];
  const float* wo_b = (const float*)d_in[8];
  const float* ep_w = (const float*)d_in[9];
  const float* ep_b = (const float*)d_in[10];
  const float* ln_g = (const float*)d_in[11];
  const float* ln_b = (const float*)d_in[12];
  float* out = (float*)d_out;

  ushort* Qb    = (ushort*)d_ws;             // 1024*256 us
  ushort* Kb    = Qb    + 262144;            // 2048*256
  ushort* VtB   = Kb    + 524288;            // 8*256*256
  ushort* qepb  = VtB   + 524288;            // 1024*512
  ushort* ctxVp = qepb  + 524288;            // 8192*256
  ushort* attEp = ctxVp + 2097152;           // 8192*512
  float*  S_p   = (float*)(attEp + 4194304); // 8192*8 f
  float*  qkb   = S_p   + 65536;             // 1024*2048 f (8MB)

  proj3_kernel<<<640, 256, 0, stream>>>(q, k, v, wq, wk, wv, Qb, Kb, VtB);
  qep_kernel<<<1024, 256, 0, stream>>>(Qb, ep_w, qepb);
  qk_kernel<<<2048, 256, 0, stream>>>(Qb, Kb, qkb);
  attn_part_kernel<<<2048, 256, 0, stream>>>(VtB, qepb, qkb, edge,
                                             ctxVp, attEp, S_p);
  reduce_outln_kernel<<<512, 256, 0, stream>>>(ctxVp, attEp, S_p, ep_w, ep_b,
                                               wo_w, wo_b, q, ln_g, ln_b, out);
}

// Round 13
// 100.859 us; speedup vs baseline: 1.0811x; 1.0811x over previous
//
#include <hip/hip_runtime.h>
#include <hip/hip_bf16.h>

// B=8, N=128, M=256, E=256, De=64, H=8, D=32
#define INV_SCALE 0.17677669529663687f
#define LN_EPS 1e-5f

typedef unsigned int uint;
typedef unsigned short ushort;
typedef __attribute__((ext_vector_type(8))) short bf16x8;   // MFMA A/B frag
typedef __attribute__((ext_vector_type(4))) float f32x4;    // MFMA C/D frag

union U8 { bf16x8 v; uint4 u4; ushort us[8]; };

__device__ __forceinline__ float blo(uint u) { return __uint_as_float(u << 16); }
__device__ __forceinline__ float bhi(uint u) { return __uint_as_float(u & 0xffff0000u); }
__device__ __forceinline__ ushort bfround(float f) {
  uint u = __float_as_uint(f);
  u += 0x7fffu + ((u >> 16) & 1u);
  return (ushort)(u >> 16);
}
__device__ __forceinline__ uint pkbf(float a, float b) {
  uint ua = __float_as_uint(a); ua += 0x7fffu + ((ua >> 16) & 1u);
  uint ub = __float_as_uint(b); ub += 0x7fffu + ((ub >> 16) & 1u);
  return (ua >> 16) | (ub & 0xffff0000u);
}
__device__ __forceinline__ float bs(ushort u) { return __uint_as_float(((uint)u) << 16); }

// ---------------- Kernel 1: Q/K/V projections (round-5-proven) ----------------
__global__ __launch_bounds__(256) void proj3_kernel(
    const float* __restrict__ q, const float* __restrict__ k, const float* __restrict__ v,
    const float* __restrict__ wq, const float* __restrict__ wk, const float* __restrict__ wv,
    ushort* __restrict__ Qb, ushort* __restrict__ Kb, ushort* __restrict__ VtB) {
  constexpr int RPB = 8;
  __shared__ float in_s[RPB][256];
  int blk = blockIdx.x;
  int t = threadIdx.x;
  const float* in; const float* w; int r0;
  if (blk < 128)      { in = q; w = wq; r0 = blk * RPB; }
  else if (blk < 384) { in = k; w = wk; r0 = (blk - 128) * RPB; }
  else                { in = v; w = wv; r0 = (blk - 384) * RPB; }
  #pragma unroll
  for (int r = 0; r < RPB; ++r) in_s[r][t] = in[(size_t)(r0 + r) * 256 + t];
  __syncthreads();
  float acc[RPB];
  #pragma unroll
  for (int r = 0; r < RPB; ++r) acc[r] = 0.f;
  const float4* wrow = reinterpret_cast<const float4*>(w + (size_t)t * 256);
  for (int j4 = 0; j4 < 64; ++j4) {
    float4 wv4 = wrow[j4];
    #pragma unroll
    for (int r = 0; r < RPB; ++r) {
      float4 iv = *reinterpret_cast<const float4*>(&in_s[r][j4 * 4]);
      acc[r] += wv4.x * iv.x + wv4.y * iv.y + wv4.z * iv.z + wv4.w * iv.w;
    }
  }
  if (blk < 128) {
    #pragma unroll
    for (int r = 0; r < RPB; ++r) Qb[(size_t)(r0 + r) * 256 + t] = bfround(acc[r]);
  } else if (blk < 384) {
    #pragma unroll
    for (int r = 0; r < RPB; ++r) Kb[(size_t)(r0 + r) * 256 + t] = bfround(acc[r]);
  } else {
    int b = r0 >> 8, m0 = r0 & 255;
    uint4 pk;
    pk.x = pkbf(acc[0], acc[1]); pk.y = pkbf(acc[2], acc[3]);
    pk.z = pkbf(acc[4], acc[5]); pk.w = pkbf(acc[6], acc[7]);
    *(uint4*)(VtB + ((size_t)(b * 256 + t)) * 256 + m0) = pk;
  }
}

// ---------------- Kernel 1b: fused qep + qk ----------------
// grid 1024 = one block per bn. qep: thread -> (h,de) x2. qk: 8 LDS-staged
// K-chunks (r4 stage pattern), thread = (h = t>>5, mi = t&31), 32-FMA dot.
// Replaces the masked-MFMA qk_kernel (7/8 wasted MFMA, ~35us -> ~8us).
__global__ __launch_bounds__(256) void qep_qk_kernel(
    const ushort* __restrict__ Qb, const ushort* __restrict__ Kb,
    const float* __restrict__ ep_w,
    ushort* __restrict__ qepb, float* __restrict__ qk) {
  __shared__ float Qs[256];
  __shared__ ushort K_s[32][264];
  int bn = blockIdx.x, t = threadIdx.x;
  int b = bn >> 7;
  Qs[t] = bs(Qb[(size_t)bn * 256 + t]);
  __syncthreads();
  // ---- qep ----
  #pragma unroll
  for (int rep = 0; rep < 2; ++rep) {
    int idx = rep * 256 + t;
    int h = idx >> 6, de = idx & 63;
    float acc = 0.f;
    #pragma unroll
    for (int d = 0; d < 32; ++d)
      acc += Qs[h * 32 + d] * ep_w[(size_t)(h * 32 + d) * 64 + de];
    qepb[(size_t)bn * 512 + idx] = bfround(acc);
  }
  // ---- qk: 8 chunks of 32 m ----
  const int h = t >> 5, mi = t & 31;
  const float* qrow = &Qs[h * 32];
  for (int mc = 0; mc < 8; ++mc) {
    #pragma unroll
    for (int it = 0; it < 4; ++it) {
      int chunk = it * 256 + t;
      int row = chunk >> 5, c8 = (chunk & 31) * 8;
      *(uint4*)&K_s[row][c8] =
          *(const uint4*)(Kb + ((size_t)(b * 256 + mc * 32 + row)) * 256 + c8);
    }
    __syncthreads();
    float s = 0.f;
    const ushort* krow = &K_s[mi][h * 32];
    #pragma unroll
    for (int d8 = 0; d8 < 4; ++d8) {
      uint4 k8 = *(const uint4*)(krow + d8 * 8);
      const float* qv = qrow + d8 * 8;
      s += blo(k8.x) * qv[0] + bhi(k8.x) * qv[1]
         + blo(k8.y) * qv[2] + bhi(k8.y) * qv[3]
         + blo(k8.z) * qv[4] + bhi(k8.z) * qv[5]
         + blo(k8.w) * qv[6] + bhi(k8.w) * qv[7];
    }
    qk[(size_t)bn * 2048 + (size_t)h * 256 + mc * 32 + mi] = s;
    __syncthreads();
  }
}

// ---------------- Kernel 2: slim partial MFMA attention (round-11, unchanged) ----------------
__global__ __launch_bounds__(256, 3) void attn_part_kernel(
    const ushort* __restrict__ VtB, const ushort* __restrict__ qepb,
    const float* __restrict__ qk, const float* __restrict__ edge,
    ushort* __restrict__ ctxVp, ushort* __restrict__ attEp, float* __restrict__ S_p) {
  __shared__ ushort etr_s[4][64][38];   // [de][m] transposed edge, wave-private
  __shared__ ushort p_s[4][16][40];     // [h][m]

  const int bid = blockIdx.x;
  const int b = bid >> 8, ng = (bid >> 3) & 31, mc = bid & 7;
  const int t = threadIdx.x;
  const int w = t >> 6, l = t & 63, g = l >> 4, c = l & 15;
  const int bn = b * 128 + ng * 4 + w;
  const int m0 = mc * 32;
  const size_t pidx = (size_t)bn * 8 + mc;

  // ---- issue qk loads first (8 dwords, dup rows for g>=2) ----
  float qkv[2][4];
  #pragma unroll
  for (int mt = 0; mt < 2; ++mt)
    #pragma unroll
    for (int r = 0; r < 4; ++r)
      qkv[mt][r] = qk[(size_t)bn * 2048 + (size_t)((g * 4 + r) & 7) * 256 + m0 + mt * 16 + c];

  // ---- qep A-fragments ----
  U8 aE0; aE0.u4 = *(const uint4*)(qepb + (size_t)bn * 512 + (c & 7) * 64 + g * 8);
  U8 aE1; aE1.u4 = *(const uint4*)(qepb + (size_t)bn * 512 + (c & 7) * 64 + 32 + g * 8);

  // ---- stage transposed edge chunk (fp32 -> bf16), wave-private ----
  {
    const float* ebase = edge + ((size_t)bn * 256 + m0) * 64 + c * 4;
    #pragma unroll
    for (int i = 0; i < 2; ++i) {
      int mb = i * 16 + g * 4;
      const float* src = ebase + (size_t)mb * 64;
      float4 e0 = *(const float4*)(src);
      float4 e1 = *(const float4*)(src + 64);
      float4 e2 = *(const float4*)(src + 128);
      float4 e3 = *(const float4*)(src + 192);
      int de4 = c * 4;
      *(uint*)&etr_s[w][de4 + 0][mb]     = pkbf(e0.x, e1.x);
      *(uint*)&etr_s[w][de4 + 0][mb + 2] = pkbf(e2.x, e3.x);
      *(uint*)&etr_s[w][de4 + 1][mb]     = pkbf(e0.y, e1.y);
      *(uint*)&etr_s[w][de4 + 1][mb + 2] = pkbf(e2.y, e3.y);
      *(uint*)&etr_s[w][de4 + 2][mb]     = pkbf(e0.z, e1.z);
      *(uint*)&etr_s[w][de4 + 2][mb + 2] = pkbf(e2.z, e3.z);
      *(uint*)&etr_s[w][de4 + 3][mb]     = pkbf(e0.w, e1.w);
      *(uint*)&etr_s[w][de4 + 3][mb + 2] = pkbf(e2.w, e3.w);
    }
  }

  // ---- hoist all 16 VtB B-fragments ----
  U8 bv[16];
  #pragma unroll
  for (int et = 0; et < 16; ++et)
    bv[et].u4 = *(const uint4*)(VtB + ((size_t)(b * 256 + et * 16 + c)) * 256 + m0 + g * 8);

  // ---- scores + exp: 2-deep edge MFMA + qk add ----
  float sS[4] = {0.f, 0.f, 0.f, 0.f};
  #pragma unroll
  for (int mt = 0; mt < 2; ++mt) {
    const float* erow = edge + ((size_t)bn * 256 + (m0 + mt * 16 + c)) * 64 + g * 8;
    float4 x0 = *(const float4*)(erow);
    float4 x1 = *(const float4*)(erow + 4);
    float4 x2 = *(const float4*)(erow + 32);
    float4 x3 = *(const float4*)(erow + 36);
    U8 be0, be1;
    be0.u4.x = pkbf(x0.x, x0.y); be0.u4.y = pkbf(x0.z, x0.w);
    be0.u4.z = pkbf(x1.x, x1.y); be0.u4.w = pkbf(x1.z, x1.w);
    be1.u4.x = pkbf(x2.x, x2.y); be1.u4.y = pkbf(x2.z, x2.w);
    be1.u4.z = pkbf(x3.x, x3.y); be1.u4.w = pkbf(x3.z, x3.w);
    f32x4 acc; acc.x = acc.y = acc.z = acc.w = 0.f;
    acc = __builtin_amdgcn_mfma_f32_16x16x32_bf16(aE0.v, be0.v, acc, 0, 0, 0);
    acc = __builtin_amdgcn_mfma_f32_16x16x32_bf16(aE1.v, be1.v, acc, 0, 0, 0);
    #pragma unroll
    for (int r = 0; r < 4; ++r) {
      float p = __expf((acc[r] + qkv[mt][r]) * INV_SCALE);
      p_s[w][g * 4 + r][mt * 16 + c] = bfround(p);
      sS[r] += p;
    }
  }
  #pragma unroll
  for (int r = 0; r < 4; ++r) {
    float sv = sS[r];
    sv += __shfl_xor(sv, 1); sv += __shfl_xor(sv, 2);
    sv += __shfl_xor(sv, 4); sv += __shfl_xor(sv, 8);
    sS[r] = sv;
  }
  if (c == 0 && g < 2) {
    #pragma unroll
    for (int r = 0; r < 4; ++r) S_p[pidx * 8 + g * 4 + r] = sS[r];
  }

  // ---- PV: ctxV partial (16 e-tiles, preloaded frags) ----
  U8 pa; pa.u4 = *(const uint4*)&p_s[w][c][g * 8];
  #pragma unroll
  for (int et = 0; et < 16; ++et) {
    f32x4 acc; acc.x = acc.y = acc.z = acc.w = 0.f;
    acc = __builtin_amdgcn_mfma_f32_16x16x32_bf16(pa.v, bv[et].v, acc, 0, 0, 0);
    int hs = et >> 1;
    if ((hs >> 2) == g) ctxVp[pidx * 256 + et * 16 + c] = bfround(acc[hs & 3]);
  }
  // ---- attnE partial (4 de-tiles, edge^T from wave-private LDS) ----
  #pragma unroll
  for (int dt = 0; dt < 4; ++dt) {
    U8 bt;
    bt.u4.x = *(const uint*)&etr_s[w][dt * 16 + c][g * 8 + 0];
    bt.u4.y = *(const uint*)&etr_s[w][dt * 16 + c][g * 8 + 2];
    bt.u4.z = *(const uint*)&etr_s[w][dt * 16 + c][g * 8 + 4];
    bt.u4.w = *(const uint*)&etr_s[w][dt * 16 + c][g * 8 + 6];
    f32x4 acc; acc.x = acc.y = acc.z = acc.w = 0.f;
    acc = __builtin_amdgcn_mfma_f32_16x16x32_bf16(pa.v, bt.v, acc, 0, 0, 0);
    if (g < 2) {
      #pragma unroll
      for (int r = 0; r < 4; ++r)
        attEp[pidx * 512 + (size_t)(g * 4 + r) * 64 + dt * 16 + c] = bfround(acc[r]);
    }
  }
}

// ---------------- Kernel 3: reduce partials + ep fold + out-proj + LN ----------------
__global__ __launch_bounds__(256) void reduce_outln_kernel(
    const ushort* __restrict__ ctxVp, const ushort* __restrict__ attEp,
    const float* __restrict__ S_p, const float* __restrict__ ep_w,
    const float* __restrict__ ep_b, const float* __restrict__ wo_w,
    const float* __restrict__ wo_b, const float* __restrict__ qin,
    const float* __restrict__ ln_g, const float* __restrict__ ln_b,
    float* __restrict__ out) {
  __shared__ float aE_s[2][512];
  __shared__ float ctx_s[2][256];
  __shared__ float o_s[2][256];
  __shared__ float rs_s[2][8];
  int bn0 = blockIdx.x * 2;
  int t = threadIdx.x;
  float cv[2];
  #pragma unroll
  for (int r = 0; r < 2; ++r) {
    float a0 = 0, a1 = 0, cc = 0;
    #pragma unroll
    for (int mcc = 0; mcc < 8; ++mcc) {
      size_t base = (size_t)(bn0 + r) * 8 + mcc;
      a0 += bs(attEp[base * 512 + t]);
      a1 += bs(attEp[base * 512 + 256 + t]);
      cc += bs(ctxVp[base * 256 + t]);
    }
    aE_s[r][t] = a0; aE_s[r][256 + t] = a1; cv[r] = cc;
  }
  if (t < 16) {
    int r = t >> 3, h = t & 7;
    float s = 0.f;
    #pragma unroll
    for (int mcc = 0; mcc < 8; ++mcc)
      s += S_p[((size_t)(bn0 + r) * 8 + mcc) * 8 + h];
    rs_s[r][h] = 1.f / s;
  }
  __syncthreads();
  {
    int h = t >> 5;
    const float* wrow = ep_w + (size_t)t * 64;
    float acc[2] = {0.f, 0.f};
    #pragma unroll
    for (int de4 = 0; de4 < 16; ++de4) {
      float4 w4 = *(const float4*)(wrow + de4 * 4);
      #pragma unroll
      for (int r = 0; r < 2; ++r) {
        float4 a4 = *(const float4*)&aE_s[r][h * 64 + de4 * 4];
        acc[r] += w4.x * a4.x + w4.y * a4.y + w4.z * a4.z + w4.w * a4.w;
      }
    }
    #pragma unroll
    for (int r = 0; r < 2; ++r)
      ctx_s[r][t] = (cv[r] + acc[r]) * rs_s[r][h] + ep_b[t];
  }
  __syncthreads();
  {
    const float4* wrow = (const float4*)(wo_w + (size_t)t * 256);
    float acc[2] = {0.f, 0.f};
    for (int j4 = 0; j4 < 64; ++j4) {
      float4 w4 = wrow[j4];
      #pragma unroll
      for (int r = 0; r < 2; ++r) {
        float4 iv = *(const float4*)&ctx_s[r][j4 * 4];
        acc[r] += w4.x * iv.x + w4.y * iv.y + w4.z * iv.z + w4.w * iv.w;
      }
    }
    float bias = wo_b[t];
    #pragma unroll
    for (int r = 0; r < 2; ++r)
      o_s[r][t] = acc[r] + bias + qin[(size_t)(bn0 + r) * 256 + t];
  }
  __syncthreads();
  {
    int wv = t >> 6, l = t & 63;
    if (wv < 2) {
      int r = wv;
      float sum = 0.f, sq = 0.f;
      #pragma unroll
      for (int kk = 0; kk < 4; ++kk) {
        float x = o_s[r][l + kk * 64];
        sum += x; sq += x * x;
      }
      #pragma unroll
      for (int ofs = 32; ofs; ofs >>= 1) {
        sum += __shfl_xor(sum, ofs);
        sq  += __shfl_xor(sq, ofs);
      }
      float mu = sum * (1.f / 256.f);
      float var = sq * (1.f / 256.f) - mu * mu;
      float rstd = rsqrtf(var + LN_EPS);
      #pragma unroll
      for (int kk = 0; kk < 4; ++kk) {
        int e = l + kk * 64;
        float x = o_s[r][e];
        out[(size_t)(bn0 + r) * 256 + e] = (x - mu) * rstd * ln_g[e] + ln_b[e];
      }
    }
  }
}

extern "C" void kernel_launch(void* const* d_in, const int* in_sizes, int n_in,
                              void* d_out, int out_size, void* d_ws, size_t ws_size,
                              hipStream_t stream) {
  const float* q    = (const float*)d_in[0];
  const float* k    = (const float*)d_in[1];
  const float* v    = (const float*)d_in[2];
  const float* edge = (const float*)d_in[3];
  const float* wq   = (const float*)d_in[4];
  const float* wk   = (const float*)d_in[5];
  const float* wv   = (const float*)d_in[6];
  const float* wo_w = (const float*)d_in[7];
  const float* wo_b = (const float*)d_in[8];
  const float* ep_w = (const float*)d_in[9];
  const float* ep_b = (const float*)d_in[10];
  const float* ln_g = (const float*)d_in[11];
  const float* ln_b = (const float*)d_in[12];
  float* out = (float*)d_out;

  ushort* Qb    = (ushort*)d_ws;             // 1024*256 us
  ushort* Kb    = Qb    + 262144;            // 2048*256
  ushort* VtB   = Kb    + 524288;            // 8*256*256
  ushort* qepb  = VtB   + 524288;            // 1024*512
  ushort* ctxVp = qepb  + 524288;            // 8192*256
  ushort* attEp = ctxVp + 2097152;           // 8192*512
  float*  S_p   = (float*)(attEp + 4194304); // 8192*8 f
  float*  qkb   = S_p   + 65536;             // 1024*2048 f (8MB)

  proj3_kernel<<<640, 256, 0, stream>>>(q, k, v, wq, wk, wv, Qb, Kb, VtB);
  qep_qk_kernel<<<1024, 256, 0, stream>>>(Qb, Kb, ep_w, qepb, qkb);
  attn_part_kernel<<<2048, 256, 0, stream>>>(VtB, qepb, qkb, edge,
                                             ctxVp, attEp, S_p);
  reduce_outln_kernel<<<512, 256, 0, stream>>>(ctxVp, attEp, S_p, ep_w, ep_b,
                                               wo_w, wo_b, q, ln_g, ln_b, out);
}